// Round 2
// baseline (103.757 us; speedup 1.0000x reference)
//
#include <hip/hip_runtime.h>

// Deformable conv (K=3,N=9,PAD=1) + BN(eval) + ReLU.  B=32 C=103 H=W=32 Cout=32.
// Round 12: round-11 dataflow (chunk-split K across two 4-wave halves, private
// per-half buffers, register-prefetch staging, PLSU=1164, row-predicated
// phase-1 staging) + PRE-PACKED f16 input: k_prep now also converts x into
// pair-interleaved f16 planes xpk[b][ch][pair][1024] (invalid channels zeroed),
// so k_fused staging is 8 uniform uint4 loads + 16 ds_write_b64 per thread
// (no cvt_pkrtz, no c<CC branches, half the global bytes, -32 VGPR prefetch
// state). Prologue now zeroes only the pad ring + slack (2240 uints), not the
// whole 74.5 KB buffer (interior is always fully staged before any read).

#define CC    103
#define COUT  32
#define KSC   5            // k-steps (K=32) per 16-channel chunk
#define RSU   34           // plane row stride (uints)
#define PLSU  1164         // 34*34=1156 +8 slack; %8=4 -> pb-quad bank offset 16
#define NPAIR 8
#define BUF_U (NPAIR * PLSU)        // 9312 uints = 37248 B per half-buffer

typedef __attribute__((ext_vector_type(8))) _Float16 f16x8;
typedef __attribute__((ext_vector_type(2))) _Float16 h2;
typedef __attribute__((ext_vector_type(2))) __fp16  fp16x2;   // cvt_pkrtz return type
typedef __attribute__((ext_vector_type(4))) float f32x4;

// ws layout (floats): wtpm frags [0,17920), wtpo frags [17920,35840), bn [35840,35904),
// xpk (uints) [35904, 35904+1835008)
#define WTPM_W 0
#define WTPO_W 17920
#define BN_W   35840
#define XPK_W  35904

// ---------- prep: f16 weight fragments (A-layout) + BN constants + x pre-pack ----
// Weight A-frag 16x16x32: lane l holds A[m=l&15][k=(l>>4)*8+j]. kl=s*32+(l>>4)*8+j;
// tap n=kl>>4; c=ch*16+(kl&15).  n>=9 / c>=103 / o>=mrows -> 0.
// x pre-pack: blocks [280,504) = (b,ch): xpk[(b*7+ch)*8192 + i*1024 + p] =
// pack_f16(x[b][ch*16+2i][p], x[b][ch*16+2i+1][p]), zeros for c>=103.
__global__ void k_prep(const float* __restrict__ x,
                       const float* __restrict__ w, const float* __restrict__ w_off,
                       const float* __restrict__ bias, const float* __restrict__ gamma,
                       const float* __restrict__ beta, const float* __restrict__ mean,
                       const float* __restrict__ var,
                       unsigned short* __restrict__ wtpm, unsigned short* __restrict__ wtpo,
                       float* __restrict__ bn, unsigned int* __restrict__ xpk) {
    int bx = blockIdx.x;
    if (bx < 280) {
        int tid = bx * 256 + threadIdx.x;
        if (tid < 71680) {
            int half_ = tid >= 35840 ? 1 : 0;
            int e = tid - half_ * 35840;
            const float* src = half_ ? w_off : w;
            unsigned short* dst = half_ ? wtpo : wtpm;
            int mrows = half_ ? 18 : 32;
            int j = e & 7, lane = (e >> 3) & 63, tile = e >> 9;
            int mt = tile & 1, chs = tile >> 1;
            int s = chs % 5, ch = chs / 5;
            int o = mt * 16 + (lane & 15);
            int kl = s * 32 + (lane >> 4) * 8 + j;
            int n = kl >> 4, c = ch * 16 + (kl & 15);
            float v = 0.f;
            if (n < 9 && c < CC && o < mrows) v = src[o * (CC * 9) + c * 9 + n];
            union { _Float16 h; unsigned short u; } cv;
            cv.h = (_Float16)v;
            dst[e] = cv.u;
        }
        if (tid < 32) {
            float inv = gamma[tid] * rsqrtf(var[tid] + 1e-5f);
            bn[tid]      = inv;
            bn[32 + tid] = beta[tid] + (bias[tid] - mean[tid]) * inv;
        }
    } else {
        int pb = bx - 280;                        // [0,224) = b*7 + ch
        int b = pb / 7, ch = pb - b * 7;
        int tl = threadIdx.x;                     // [0,256): uint4 at pixel tl*4
        const float* xb = x + b * (CC * 1024) + tl * 4;
        unsigned int* dst = xpk + pb * 8192 + tl * 4;
#pragma unroll
        for (int i = 0; i < NPAIR; i++) {
            int c = ch * 16 + 2 * i;
            float4 L = make_float4(0.f, 0.f, 0.f, 0.f);
            float4 M = make_float4(0.f, 0.f, 0.f, 0.f);
            if (c < CC)     L = *(const float4*)(xb + c * 1024);
            if (c + 1 < CC) M = *(const float4*)(xb + (c + 1) * 1024);
            union { fp16x2 hh; unsigned u; } p0, p1, p2, p3;
            p0.hh = __builtin_amdgcn_cvt_pkrtz(L.x, M.x);
            p1.hh = __builtin_amdgcn_cvt_pkrtz(L.y, M.y);
            p2.hh = __builtin_amdgcn_cvt_pkrtz(L.z, M.z);
            p3.hh = __builtin_amdgcn_cvt_pkrtz(L.w, M.w);
            *(uint4*)(dst + i * 1024) = make_uint4(p0.u, p1.u, p2.u, p3.u);
        }
    }
}

// ---------- fused kernel ----------
__global__ void __launch_bounds__(512, 4)
k_fused(const unsigned int* __restrict__ xpk, const float* __restrict__ b_off,
        const unsigned short* __restrict__ wtpo, const unsigned short* __restrict__ wtpm,
        const float* __restrict__ bn, float* __restrict__ out) {
    __shared__ unsigned int ldsp[2 * BUF_U];
    __shared__ float exch[18 * 64];

    int bid = blockIdx.x;
    int b   = (bid & 7) * 4 + ((bid >> 3) & 3);   // XCD swizzle
    int pxg = bid >> 5;

    int t = threadIdx.x, lane = t & 63, wv = t >> 6;
    int kh = wv >> 2;                 // chunk-half: 0 -> chunks {1,3,5}, 1 -> {0,2,4,6}
    int pxl = (wv & 3) * 16 + (lane & 15);
    int px  = pxg * 64 + pxl;
    int h = px >> 5, wq = px & 31;
    int kg = lane >> 4;               // quad
    int hi = kg >> 1;
    int pb = (kg & 1) * 4;            // pair-plane base

    unsigned int* mybuf = ldsp + kh * BUF_U;

    int tl = t & 255;
    int sr = tl >> 3, sk = (tl & 7) * 4;          // staging row / col group

    // phase-1 consumes only padded rows 2*pxg..2*pxg+3 -> staging rows
    // sr in [2*pxg-1, 2*pxg+2] clipped (pad rows 0/33 stay prologue-zero).
    int r0 = 2 * pxg - 1; if (r0 < 0) r0 = 0;
    int r1 = 2 * pxg + 2; if (r1 > 31) r1 = 31;
    bool rowact = (sr >= r0 && sr <= r1);

    // per-lane tap tables (lo-quads taps 0,2,4,6,8; hi-quads 1,3,5,7,8; tap8 dup = zero wt)
    const int KYL[5] = {0,0,1,2,2}, KXL[5] = {0,2,1,0,2};
    const int KYH[5] = {0,1,1,2,2}, KXH[5] = {1,0,2,1,2};
    const int TAPL[5] = {0,2,4,6,8}, TAPH[5] = {1,3,5,7,8};
    int myky[5], mykx[5], mytap[5];
#pragma unroll
    for (int s = 0; s < 5; s++) {
        myky[s] = hi ? KYH[s] : KYL[s];
        mykx[s] = hi ? KXH[s] : KXL[s];
        mytap[s] = hi ? TAPH[s] : TAPL[s];
    }

    // register-prefetch staging: 8 uint4 live across compute (~32 VGPR)
    uint4 U[NPAIR];
    auto loadx = [&](int ch, bool full) {
        if (!full && !rowact) return;             // phase-1 partial: <=4 rows
        const unsigned int* s0 = xpk + (b * 7 + ch) * 8192 + tl * 4;
#pragma unroll
        for (int i = 0; i < NPAIR; i++) U[i] = *(const uint4*)(s0 + i * 1024);
    };
    auto packwrite = [&](int ch, bool full) {
        if (!full && !rowact) return;
        unsigned int* dstb = mybuf + (sr + 1) * RSU + 2 + sk;
#pragma unroll
        for (int i = 0; i < NPAIR; i++) {
            *(uint2*)(dstb + i * PLSU)     = make_uint2(U[i].x, U[i].y);
            *(uint2*)(dstb + i * PLSU + 2) = make_uint2(U[i].z, U[i].w);
        }
    };

    auto chunk1 = [&](int it) { return kh ? (2 * it) : (it < 3 ? 2 * it + 1 : -1); };
    auto chunk2 = [&](int it) { return kh ? (6 - 2 * it) : (it < 3 ? 5 - 2 * it : -1); };
    int fullIt = 2 + kh;              // last phase-1 staging stays resident into phase 2

    f32x4 acc0 = {0.f, 0.f, 0.f, 0.f};
    f32x4 acc1 = {0.f, 0.f, 0.f, 0.f};

    // prologue: prefetch first chunk (partial); zero only pad ring + slack:
    // per plane: row0 [0,34) + row33&slack [1122,1164) + cols{0,1} of rows 1..32.
    loadx(chunk1(0), false);
    for (int i = t; i < 2240; i += 512) {
        int plane = i / 140, r = i - plane * 140;
        int off;
        if (r < 34)      off = r;
        else if (r < 76) off = 1122 + (r - 34);
        else { int rr = (r - 76) >> 1; off = (rr + 1) * 34 + ((r - 76) & 1); }
        ldsp[(plane >> 3) * BUF_U + (plane & 7) * PLSU + off] = 0u;
    }
    __syncthreads();

    // ================= phase 1: offset conv =================
    for (int it = 0; it < 4; it++) {
        int ch = chunk1(it);
        if (ch >= 0) packwrite(ch, it == fullIt);
        __syncthreads();                          // staging visible
        int nx = (it < 3) ? chunk1(it + 1) : -1;
        if (nx >= 0) loadx(nx, it + 1 == fullIt); // globals hide under compute
        if (ch >= 0) {
            const unsigned short* wch = wtpo + ch * 5120;
#pragma unroll
            for (int s = 0; s < KSC; s++) {
                const unsigned int* cell = mybuf + pb * PLSU
                    + (h + myky[s]) * RSU + 1 + (wq + mykx[s]);
                union { unsigned u[4]; f16x8 v; } bu;
#pragma unroll
                for (int jj = 0; jj < 4; jj++) bu.u[jj] = cell[jj * PLSU];
                f16x8 a0 = *(const f16x8*)(wch + s * 1024 + lane * 8);
                f16x8 a1 = *(const f16x8*)(wch + s * 1024 + 512 + lane * 8);
                acc0 = __builtin_amdgcn_mfma_f32_16x16x32_f16(a0, bu.v, acc0, 0, 0, 0);
                acc1 = __builtin_amdgcn_mfma_f32_16x16x32_f16(a1, bu.v, acc1, 0, 0, 0);
            }
        }
        __syncthreads();                          // compute done before next overwrite
    }

    // ---- reduce offset partials across halves (C-layout: row=kg*4+reg, col=pxl)
    if (kh == 0) {
        float* ex = exch + pxl;
#pragma unroll
        for (int reg = 0; reg < 4; reg++) ex[(kg * 4 + reg) * 64] = acc0[reg];
        if (kg == 0) { ex[16 * 64] = acc1[0]; ex[17 * 64] = acc1[1]; }
    }
    __syncthreads();
    if (kh == 1) {
        float* ex = exch + pxl;
#pragma unroll
        for (int reg = 0; reg < 4; reg++) ex[(kg * 4 + reg) * 64] += acc0[reg];
        if (kg == 0) { ex[16 * 64] += acc1[0]; ex[17 * 64] += acc1[1]; }
    }
    __syncthreads();

    // ---- geometry (once; 5 slots per lane)
    int cofs[KSC];
    h2  W[KSC][4];
#pragma unroll
    for (int s = 0; s < KSC; s++) {
        int tap = mytap[s];
        float oy = exch[tap * 64 + pxl] + b_off[tap];
        float ox = exch[(9 + tap) * 64 + pxl] + b_off[9 + tap];
        float py  = (float)(h + myky[s]) + oy;    // padded coords
        float pxx = (float)(wq + mykx[s]) + ox;
        py  = fminf(fmaxf(py, 0.f), 33.f);
        pxx = fminf(fmaxf(pxx, 0.f), 33.f);
        int y0 = min((int)py, 32);
        int x0 = min((int)pxx, 32);
        float fy = py - (float)y0;
        float fx = pxx - (float)x0;
        float w00 = (1.f - fy) * (1.f - fx), w01 = (1.f - fy) * fx;
        float w10 = fy * (1.f - fx),          w11 = fy * fx;
        W[s][0] = (h2){(_Float16)w00, (_Float16)w00};
        W[s][1] = (h2){(_Float16)w01, (_Float16)w01};
        W[s][2] = (h2){(_Float16)w10, (_Float16)w10};
        W[s][3] = (h2){(_Float16)w11, (_Float16)w11};
        cofs[s] = pb * PLSU + y0 * RSU + 1 + x0;
    }

    // ================= phase 2: deformable conv (chunks reversed; first resident) ====
    acc0 = (f32x4){0.f, 0.f, 0.f, 0.f};
    acc1 = (f32x4){0.f, 0.f, 0.f, 0.f};
    for (int it = 0; it < 4; it++) {
        int ch = chunk2(it);
        if (it > 0) {
            if (ch >= 0) packwrite(ch, true);
            else {  // kh==0, it==3: publish main partials into kh0's dead buffer
                float* e = (float*)ldsp + pxl;
#pragma unroll
                for (int reg = 0; reg < 4; reg++) {
                    e[(kg * 4 + reg) * 64]      = acc0[reg];
                    e[(16 + kg * 4 + reg) * 64] = acc1[reg];
                }
            }
        }
        __syncthreads();
        int nx = (it < 3) ? chunk2(it + 1) : -1;
        if (nx >= 0) loadx(nx, true);
        if (ch >= 0) {
            const unsigned short* wch = wtpm + ch * 5120;
#pragma unroll
            for (int s = 0; s < KSC; s++) {
                const unsigned int* cell = mybuf + cofs[s];
                union { unsigned u[4]; f16x8 v; } bu;
#pragma unroll
                for (int jj = 0; jj < 4; jj++) {
                    union { unsigned u; h2 hh; } t0, t1, b0, b1;
                    t0.u = cell[jj * PLSU];
                    t1.u = cell[jj * PLSU + 1];
                    b0.u = cell[jj * PLSU + RSU];
                    b1.u = cell[jj * PLSU + RSU + 1];
                    h2 sm = t0.hh * W[s][0] + t1.hh * W[s][1]
                          + b0.hh * W[s][2] + b1.hh * W[s][3];
                    union { h2 hh; unsigned u; } r; r.hh = sm;
                    bu.u[jj] = r.u;
                }
                f16x8 a0 = *(const f16x8*)(wch + s * 1024 + lane * 8);
                f16x8 a1 = *(const f16x8*)(wch + s * 1024 + 512 + lane * 8);
                acc0 = __builtin_amdgcn_mfma_f32_16x16x32_f16(a0, bu.v, acc0, 0, 0, 0);
                acc1 = __builtin_amdgcn_mfma_f32_16x16x32_f16(a1, bu.v, acc1, 0, 0, 0);
            }
        }
        __syncthreads();
    }

    // ---- final reduce + BN + ReLU + store (kh1 adds kh0's published partials)
    if (kh == 1) {
        const float* ex2 = (const float*)ldsp;
        float* op = out + (size_t)b * COUT * 1024 + px;
#pragma unroll
        for (int mt = 0; mt < 2; mt++) {
            f32x4 a = mt ? acc1 : acc0;
#pragma unroll
            for (int reg = 0; reg < 4; reg++) {
                int o = mt * 16 + kg * 4 + reg;
                float tot = a[reg] + ex2[o * 64 + pxl];
                float v = tot * bn[o] + bn[32 + o];
                op[o * 1024] = fmaxf(v, 0.f);
            }
        }
    }
}

extern "C" void kernel_launch(void* const* d_in, const int* in_sizes, int n_in,
                              void* d_out, int out_size, void* d_ws, size_t ws_size,
                              hipStream_t stream) {
    const float* x      = (const float*)d_in[0];
    const float* w_off  = (const float*)d_in[1];
    const float* b_off  = (const float*)d_in[2];
    const float* w      = (const float*)d_in[3];
    const float* bias   = (const float*)d_in[4];
    const float* gamma  = (const float*)d_in[5];
    const float* beta   = (const float*)d_in[6];
    const float* rmean  = (const float*)d_in[7];
    const float* rvar   = (const float*)d_in[8];
    float* out = (float*)d_out;

    float* ws = (float*)d_ws;
    unsigned short* wtpm = (unsigned short*)(ws + WTPM_W);
    unsigned short* wtpo = (unsigned short*)(ws + WTPO_W);
    float*          bn   = ws + BN_W;
    unsigned int*   xpk  = (unsigned int*)(ws + XPK_W);

    k_prep <<<504, 256, 0, stream>>>(x, w, w_off, bias, gamma, beta, rmean, rvar,
                                     wtpm, wtpo, bn, xpk);
    k_fused<<<512, 512, 0, stream>>>(xpk, b_off, wtpo, wtpm, bn, out);
}

// Round 4
// 101.954 us; speedup vs baseline: 1.0177x; 1.0177x over previous
//
#include <hip/hip_runtime.h>

// Deformable conv (K=3,N=9,PAD=1) + BN(eval) + ReLU.  B=32 C=103 H=W=32 Cout=32.
// Round 14: round-13 pixel-major LDS layout, with the compile fix: hot-path
// 16B vectors use ext_vector_type(4) uint (u32x4) so __builtin_nontemporal_load
// accepts them (HIP's uint4 class type is rejected by the builtin).
//   phase-1 gather: 1 ds_read_b128 per k-step (was 4 ds_read_b32)
//   phase-2 gather: 4 ds_read_b128 per k-step, imm offsets (was 16 ds_read_b32)
//   staging: 8 ds_write_b128 (was 16 ds_write_b64), strided-column map
//   xpk pre-packed pixel-major -> staged loads are verbatim stores
//   staging loads nontemporal (protect L1 residency of weight A-frags)

#define CC    103
#define COUT  32
#define KSC   5            // k-steps (K=32) per 16-channel chunk
#define RSU   34           // slots per plane row
#define GS_D  4656         // group stride in dwords = 1164 slots*4; %32==16
#define BUF_U (2 * GS_D)   // 9312 dwords = 37248 B per half-buffer

typedef __attribute__((ext_vector_type(8))) _Float16 f16x8;
typedef __attribute__((ext_vector_type(2))) _Float16 h2;
typedef __attribute__((ext_vector_type(2))) __fp16  fp16x2;   // cvt_pkrtz return type
typedef __attribute__((ext_vector_type(4))) float f32x4;
typedef __attribute__((ext_vector_type(4))) unsigned int u32x4;

// ws layout (floats): wtpm frags [0,17920), wtpo frags [17920,35840), bn [35840,35904),
// xpk (uints) [35904, 35904+1835008)
#define WTPM_W 0
#define WTPO_W 17920
#define BN_W   35840
#define XPK_W  35904

// ---------- prep: f16 weight fragments (A-layout) + BN constants + x pre-pack ----
// Weight A-frag 16x16x32: lane l holds A[m=l&15][k=(l>>4)*8+j]. kl=s*32+(l>>4)*8+j;
// tap n=kl>>4; c=ch*16+(kl&15).  n>=9 / c>=103 / o>=mrows -> 0.
// x pre-pack (blocks [280,504) = b*7+ch), pixel-major: for group g, pixel p:
// xpk[(b*7+ch)*8192 + g*4096 + p*4 + j] = pack_f16(x[c],x[c+1]) at pixel p,
// where pair = g*4+j, c = ch*16+2*pair; zeros for c>=103.
__global__ void k_prep(const float* __restrict__ x,
                       const float* __restrict__ w, const float* __restrict__ w_off,
                       const float* __restrict__ bias, const float* __restrict__ gamma,
                       const float* __restrict__ beta, const float* __restrict__ mean,
                       const float* __restrict__ var,
                       unsigned short* __restrict__ wtpm, unsigned short* __restrict__ wtpo,
                       float* __restrict__ bn, unsigned int* __restrict__ xpk) {
    int bx = blockIdx.x;
    if (bx < 280) {
        int tid = bx * 256 + threadIdx.x;
        if (tid < 71680) {
            int half_ = tid >= 35840 ? 1 : 0;
            int e = tid - half_ * 35840;
            const float* src = half_ ? w_off : w;
            unsigned short* dst = half_ ? wtpo : wtpm;
            int mrows = half_ ? 18 : 32;
            int j = e & 7, lane = (e >> 3) & 63, tile = e >> 9;
            int mt = tile & 1, chs = tile >> 1;
            int s = chs % 5, ch = chs / 5;
            int o = mt * 16 + (lane & 15);
            int kl = s * 32 + (lane >> 4) * 8 + j;
            int n = kl >> 4, c = ch * 16 + (kl & 15);
            float v = 0.f;
            if (n < 9 && c < CC && o < mrows) v = src[o * (CC * 9) + c * 9 + n];
            union { _Float16 h; unsigned short u; } cv;
            cv.h = (_Float16)v;
            dst[e] = cv.u;
        }
        if (tid < 32) {
            float inv = gamma[tid] * rsqrtf(var[tid] + 1e-5f);
            bn[tid]      = inv;
            bn[32 + tid] = beta[tid] + (bias[tid] - mean[tid]) * inv;
        }
    } else {
        int pb = bx - 280;                        // [0,224) = b*7 + ch
        int b = pb / 7, ch = pb - b * 7;
        int tl = threadIdx.x;                     // [0,256): pixels 4*tl..4*tl+3
        const float* xb = x + b * (CC * 1024) + tl * 4;
        unsigned int* dst = xpk + pb * 8192 + tl * 16;
        unsigned d[8][4];
#pragma unroll
        for (int i = 0; i < 8; i++) {
            int c = ch * 16 + 2 * i;
            float4 L = make_float4(0.f, 0.f, 0.f, 0.f);
            float4 M = make_float4(0.f, 0.f, 0.f, 0.f);
            if (c < CC)     L = *(const float4*)(xb + c * 1024);
            if (c + 1 < CC) M = *(const float4*)(xb + (c + 1) * 1024);
            union { fp16x2 hh; unsigned u; } p0, p1, p2, p3;
            p0.hh = __builtin_amdgcn_cvt_pkrtz(L.x, M.x);
            p1.hh = __builtin_amdgcn_cvt_pkrtz(L.y, M.y);
            p2.hh = __builtin_amdgcn_cvt_pkrtz(L.z, M.z);
            p3.hh = __builtin_amdgcn_cvt_pkrtz(L.w, M.w);
            d[i][0] = p0.u; d[i][1] = p1.u; d[i][2] = p2.u; d[i][3] = p3.u;
        }
#pragma unroll
        for (int q = 0; q < 4; q++) {
            *(u32x4*)(dst + q * 4)        = (u32x4){d[0][q], d[1][q], d[2][q], d[3][q]};
            *(u32x4*)(dst + 4096 + q * 4) = (u32x4){d[4][q], d[5][q], d[6][q], d[7][q]};
        }
    }
}

// ---------- fused kernel ----------
__global__ void __launch_bounds__(512, 4)
k_fused(const unsigned int* __restrict__ xpk, const float* __restrict__ b_off,
        const unsigned short* __restrict__ wtpo, const unsigned short* __restrict__ wtpm,
        const float* __restrict__ bn, float* __restrict__ out) {
    __shared__ __align__(16) unsigned int ldsp[2 * BUF_U];
    __shared__ float exch[18 * 64];

    int bid = blockIdx.x;
    int b   = (bid & 7) * 4 + ((bid >> 3) & 3);   // XCD swizzle
    int pxg = bid >> 5;

    int t = threadIdx.x, lane = t & 63, wv = t >> 6;
    int kh = wv >> 2;                 // chunk-half: 0 -> chunks {1,3,5}, 1 -> {0,2,4,6}
    int pxl = (wv & 3) * 16 + (lane & 15);
    int px  = pxg * 64 + pxl;
    int h = px >> 5, wq = px & 31;
    int kg = lane >> 4;               // quad
    int hi = kg >> 1;
    int kgrp = kg & 1;                // group select (planes 0-3 / 4-7)

    unsigned int* mybuf = ldsp + kh * BUF_U;

    int tl = t & 255;
    int r = tl >> 3, c = tl & 7;      // staging row / column-residue (cols c+8k)

    // phase-1 consumes only padded rows 2*pxg..2*pxg+3 -> staging rows
    // r in [2*pxg-1, 2*pxg+2] clipped (pad rows 0/33 stay prologue-zero).
    int r0 = 2 * pxg - 1; if (r0 < 0) r0 = 0;
    int r1 = 2 * pxg + 2; if (r1 > 31) r1 = 31;
    bool rowact = (r >= r0 && r <= r1);

    // per-lane tap tables (lo-quads taps 0,2,4,6,8; hi-quads 1,3,5,7,8; tap8 dup = zero wt)
    const int KYL[5] = {0,0,1,2,2}, KXL[5] = {0,2,1,0,2};
    const int KYH[5] = {0,1,1,2,2}, KXH[5] = {1,0,2,1,2};
    const int TAPL[5] = {0,2,4,6,8}, TAPH[5] = {1,3,5,7,8};
    int myky[5], mykx[5], mytap[5];
#pragma unroll
    for (int s = 0; s < 5; s++) {
        myky[s] = hi ? KYH[s] : KYL[s];
        mykx[s] = hi ? KXH[s] : KXL[s];
        mytap[s] = hi ? TAPH[s] : TAPL[s];
    }

    // register-prefetch staging: 8 u32x4 live across compute (~32 VGPR)
    u32x4 U[8];
    auto loadx = [&](int ch, bool full) {
        if (!full && !rowact) return;             // phase-1 partial: <=4 rows
        const unsigned int* s0 = xpk + (b * 7 + ch) * 8192 + (r * 32 + c) * 4;
#pragma unroll
        for (int g = 0; g < 2; g++)
#pragma unroll
        for (int k = 0; k < 4; k++)
            U[g * 4 + k] = __builtin_nontemporal_load(
                               (const u32x4*)(s0 + g * 4096 + k * 32));
    };
    auto packwrite = [&](int ch, bool full) {
        if (!full && !rowact) return;
        unsigned int* dstb = mybuf + ((r + 1) * RSU + 2 + c) * 4;
#pragma unroll
        for (int g = 0; g < 2; g++)
#pragma unroll
        for (int k = 0; k < 4; k++)
            *(u32x4*)(dstb + g * GS_D + k * 32) = U[g * 4 + k];
    };

    auto chunk1 = [&](int it) { return kh ? (2 * it) : (it < 3 ? 2 * it + 1 : -1); };
    auto chunk2 = [&](int it) { return kh ? (6 - 2 * it) : (it < 3 ? 5 - 2 * it : -1); };
    int fullIt = 2 + kh;              // last phase-1 staging stays resident into phase 2

    f32x4 acc0 = {0.f, 0.f, 0.f, 0.f};
    f32x4 acc1 = {0.f, 0.f, 0.f, 0.f};

    // prologue: prefetch first chunk (partial); zero only pad ring + slack:
    // per group: row0 slots [0,34) + row33&slack slots [1122,1164) + cols{0,1}
    // of rows 1..32.  4 groups total (2 per half).
    loadx(chunk1(0), false);
    {
        u32x4 z4 = (u32x4){0u, 0u, 0u, 0u};
        for (int i = t; i < 560; i += 512) {
            int grp = i / 140, rr = i - grp * 140;
            int off;
            if (rr < 34)      off = rr;
            else if (rr < 76) off = 1122 + (rr - 34);
            else { int q2 = (rr - 76) >> 1; off = (q2 + 1) * 34 + ((rr - 76) & 1); }
            *(u32x4*)(ldsp + (grp >> 1) * BUF_U + (grp & 1) * GS_D + off * 4) = z4;
        }
    }
    __syncthreads();

    // ================= phase 1: offset conv =================
    for (int it = 0; it < 4; it++) {
        int ch = chunk1(it);
        if (ch >= 0) packwrite(ch, it == fullIt);
        __syncthreads();                          // staging visible
        int nx = (it < 3) ? chunk1(it + 1) : -1;
        if (nx >= 0) loadx(nx, it + 1 == fullIt); // globals hide under compute
        if (ch >= 0) {
            const unsigned short* wch = wtpo + ch * 5120;
#pragma unroll
            for (int s = 0; s < KSC; s++) {
                const unsigned int* cell = mybuf + kgrp * GS_D
                    + ((h + myky[s]) * RSU + 1 + (wq + mykx[s])) * 4;
                union { u32x4 q; f16x8 v; } bu;
                bu.q = *(const u32x4*)cell;
                f16x8 a0 = *(const f16x8*)(wch + s * 1024 + lane * 8);
                f16x8 a1 = *(const f16x8*)(wch + s * 1024 + 512 + lane * 8);
                acc0 = __builtin_amdgcn_mfma_f32_16x16x32_f16(a0, bu.v, acc0, 0, 0, 0);
                acc1 = __builtin_amdgcn_mfma_f32_16x16x32_f16(a1, bu.v, acc1, 0, 0, 0);
            }
        }
        __syncthreads();                          // compute done before next overwrite
    }

    // ---- reduce offset partials across halves (C-layout: row=kg*4+reg, col=pxl)
    if (kh == 0) {
        float* ex = exch + pxl;
#pragma unroll
        for (int reg = 0; reg < 4; reg++) ex[(kg * 4 + reg) * 64] = acc0[reg];
        if (kg == 0) { ex[16 * 64] = acc1[0]; ex[17 * 64] = acc1[1]; }
    }
    __syncthreads();
    if (kh == 1) {
        float* ex = exch + pxl;
#pragma unroll
        for (int reg = 0; reg < 4; reg++) ex[(kg * 4 + reg) * 64] += acc0[reg];
        if (kg == 0) { ex[16 * 64] += acc1[0]; ex[17 * 64] += acc1[1]; }
    }
    __syncthreads();

    // ---- geometry (once; 5 slots per lane)
    int cofs[KSC];
    h2  W[KSC][4];
#pragma unroll
    for (int s = 0; s < KSC; s++) {
        int tap = mytap[s];
        float oy = exch[tap * 64 + pxl] + b_off[tap];
        float ox = exch[(9 + tap) * 64 + pxl] + b_off[9 + tap];
        float py  = (float)(h + myky[s]) + oy;    // padded coords
        float pxx = (float)(wq + mykx[s]) + ox;
        py  = fminf(fmaxf(py, 0.f), 33.f);
        pxx = fminf(fmaxf(pxx, 0.f), 33.f);
        int y0 = min((int)py, 32);
        int x0 = min((int)pxx, 32);
        float fy = py - (float)y0;
        float fx = pxx - (float)x0;
        float w00 = (1.f - fy) * (1.f - fx), w01 = (1.f - fy) * fx;
        float w10 = fy * (1.f - fx),          w11 = fy * fx;
        W[s][0] = (h2){(_Float16)w00, (_Float16)w00};
        W[s][1] = (h2){(_Float16)w01, (_Float16)w01};
        W[s][2] = (h2){(_Float16)w10, (_Float16)w10};
        W[s][3] = (h2){(_Float16)w11, (_Float16)w11};
        cofs[s] = kgrp * GS_D + (y0 * RSU + 1 + x0) * 4;
    }

    // ================= phase 2: deformable conv (chunks reversed; first resident) ====
    acc0 = (f32x4){0.f, 0.f, 0.f, 0.f};
    acc1 = (f32x4){0.f, 0.f, 0.f, 0.f};
    for (int it = 0; it < 4; it++) {
        int ch = chunk2(it);
        if (it > 0) {
            if (ch >= 0) packwrite(ch, true);
            else {  // kh==0, it==3: publish main partials into kh0's dead buffer
                float* e = (float*)ldsp + pxl;
#pragma unroll
                for (int reg = 0; reg < 4; reg++) {
                    e[(kg * 4 + reg) * 64]      = acc0[reg];
                    e[(16 + kg * 4 + reg) * 64] = acc1[reg];
                }
            }
        }
        __syncthreads();
        int nx = (it < 3) ? chunk2(it + 1) : -1;
        if (nx >= 0) loadx(nx, true);
        if (ch >= 0) {
            const unsigned short* wch = wtpm + ch * 5120;
#pragma unroll
            for (int s = 0; s < KSC; s++) {
                const unsigned int* cell = mybuf + cofs[s];
                union { u32x4 q; unsigned a[4]; } T0, T1, B0, B1;
                T0.q = *(const u32x4*)(cell);
                T1.q = *(const u32x4*)(cell + 4);
                B0.q = *(const u32x4*)(cell + 4 * RSU);
                B1.q = *(const u32x4*)(cell + 4 * RSU + 4);
                union { unsigned u[4]; f16x8 v; } bu;
#pragma unroll
                for (int jj = 0; jj < 4; jj++) {
                    union { unsigned u; h2 hh; } t0, t1, b0, b1, rr;
                    t0.u = T0.a[jj];
                    t1.u = T1.a[jj];
                    b0.u = B0.a[jj];
                    b1.u = B1.a[jj];
                    rr.hh = t0.hh * W[s][0] + t1.hh * W[s][1]
                          + b0.hh * W[s][2] + b1.hh * W[s][3];
                    bu.u[jj] = rr.u;
                }
                f16x8 a0 = *(const f16x8*)(wch + s * 1024 + lane * 8);
                f16x8 a1 = *(const f16x8*)(wch + s * 1024 + 512 + lane * 8);
                acc0 = __builtin_amdgcn_mfma_f32_16x16x32_f16(a0, bu.v, acc0, 0, 0, 0);
                acc1 = __builtin_amdgcn_mfma_f32_16x16x32_f16(a1, bu.v, acc1, 0, 0, 0);
            }
        }
        __syncthreads();
    }

    // ---- final reduce + BN + ReLU + store (kh1 adds kh0's published partials)
    if (kh == 1) {
        const float* ex2 = (const float*)ldsp;
        float* op = out + (size_t)b * COUT * 1024 + px;
#pragma unroll
        for (int mt = 0; mt < 2; mt++) {
            f32x4 a = mt ? acc1 : acc0;
#pragma unroll
            for (int reg = 0; reg < 4; reg++) {
                int o = mt * 16 + kg * 4 + reg;
                float tot = a[reg] + ex2[o * 64 + pxl];
                float v = tot * bn[o] + bn[32 + o];
                __builtin_nontemporal_store(fmaxf(v, 0.f), &op[o * 1024]);
            }
        }
    }
}

extern "C" void kernel_launch(void* const* d_in, const int* in_sizes, int n_in,
                              void* d_out, int out_size, void* d_ws, size_t ws_size,
                              hipStream_t stream) {
    const float* x      = (const float*)d_in[0];
    const float* w_off  = (const float*)d_in[1];
    const float* b_off  = (const float*)d_in[2];
    const float* w      = (const float*)d_in[3];
    const float* bias   = (const float*)d_in[4];
    const float* gamma  = (const float*)d_in[5];
    const float* beta   = (const float*)d_in[6];
    const float* rmean  = (const float*)d_in[7];
    const float* rvar   = (const float*)d_in[8];
    float* out = (float*)d_out;

    float* ws = (float*)d_ws;
    unsigned short* wtpm = (unsigned short*)(ws + WTPM_W);
    unsigned short* wtpo = (unsigned short*)(ws + WTPO_W);
    float*          bn   = ws + BN_W;
    unsigned int*   xpk  = (unsigned int*)(ws + XPK_W);

    k_prep <<<504, 256, 0, stream>>>(x, w, w_off, bias, gamma, beta, rmean, rvar,
                                     wtpm, wtpo, bn, xpk);
    k_fused<<<512, 512, 0, stream>>>(xpk, b_off, wtpo, wtpm, bn, out);
}